// Round 3
// baseline (550.181 us; speedup 1.0000x reference)
//
#include <hip/hip_runtime.h>

#define NSEG   4194304
#define BLOCK  256
#define ITEMS  16
#define TILE   (BLOCK * ITEMS)     // 4096
#define NTILES (NSEG / TILE)       // 1024
#define WAVES  (BLOCK / 64)        // 4

static_assert(NSEG % TILE == 0, "tile must divide N");

// Segment monoid: T = sum of angles, C/S = sum of cos/sin of segment-local
// inclusive cumulative angle. combine(a, b) = "a followed by b".
__device__ __forceinline__ void combineSeg(float aT, float aC, float aS,
                                           float bT, float bC, float bS,
                                           float& oT, float& oC, float& oS) {
    float s, c;
    __sincosf(aT, &s, &c);
    oT = aT + bT;
    oC = aC + c * bC - s * bS;
    oS = aS + s * bC + c * bS;
}

// Flag protocol: anything other than 1/2 (incl. the 0xAA poison) = not ready.
#define FLAG_PARTIAL 1
#define FLAG_PREFIX  2

__global__ __launch_bounds__(BLOCK) void k_fused(
        const float* __restrict__ vec, const float* __restrict__ vec2,
        const float* __restrict__ the0, const float* __restrict__ the02,
        const float* __restrict__ PS, const float* __restrict__ PE,
        const float* __restrict__ dl,
        int* __restrict__ flags, float4* __restrict__ part,
        float4* __restrict__ pref, float* __restrict__ out) {
    const int b = blockIdx.x;          // tile index within curve
    const int c = blockIdx.y;          // curve
    const int t = threadIdx.x;
    const int lane = t & 63, wave = t >> 6;
    const int cid = c * NTILES + b;
    const float* __restrict__ v = c ? vec2 : vec;

    __shared__ float sW[WAVES];
    __shared__ float sRC[WAVES], sRS[WAVES];
    __shared__ float sWx[WAVES], sWy[WAVES];
    __shared__ float sAgg[3];
    __shared__ float sExcl[3];

    // ---------------- Phase 1: tile aggregate (T, C, S) — round-1 K1 body ----
    const float4* __restrict__ p =
        reinterpret_cast<const float4*>(v + (size_t)b * TILE) +
        (size_t)t * (ITEMS / 4);
    float vals[ITEMS];
#pragma unroll
    for (int q = 0; q < ITEMS / 4; ++q) {
        float4 a = p[q];
        vals[q * 4 + 0] = a.x; vals[q * 4 + 1] = a.y;
        vals[q * 4 + 2] = a.z; vals[q * 4 + 3] = a.w;
    }
    float tsum = 0.f;
#pragma unroll
    for (int k = 0; k < ITEMS; ++k) tsum += vals[k];

    float incl = tsum;
#pragma unroll
    for (int d = 1; d < 64; d <<= 1) {
        float o = __shfl_up(incl, d, 64);
        if (lane >= d) incl += o;
    }
    if (lane == 63) sW[wave] = incl;
    __syncthreads();
    float wpre = 0.f, tot = 0.f;
#pragma unroll
    for (int w = 0; w < WAVES; ++w) {
        float x = sW[w];
        if (w < wave) wpre += x;
        tot += x;
    }
    const float excl = wpre + incl - tsum;   // per-thread tile-local angle base

    float run = excl, C = 0.f, S = 0.f;
#pragma unroll
    for (int k = 0; k < ITEMS; ++k) {
        run += vals[k];
        float sn, cs;
        __sincosf(run, &sn, &cs);
        C += cs; S += sn;
    }
#pragma unroll
    for (int d = 32; d > 0; d >>= 1) {
        C += __shfl_down(C, d, 64);
        S += __shfl_down(S, d, 64);
    }
    if (lane == 0) { sRC[wave] = C; sRS[wave] = S; }
    __syncthreads();
    if (t == 0) {
        float Ct = 0.f, St = 0.f;
#pragma unroll
        for (int w = 0; w < WAVES; ++w) { Ct += sRC[w]; St += sRS[w]; }
        sAgg[0] = tot; sAgg[1] = Ct; sAgg[2] = St;
        part[cid] = make_float4(tot, Ct, St, 0.f);
        __hip_atomic_store(&flags[cid], FLAG_PARTIAL,
                           __ATOMIC_RELEASE, __HIP_MEMORY_SCOPE_AGENT);
    }
    __syncthreads();

    // ---------------- Phase 2: wave-0 windowed lookback ----------------
    if (wave == 0) {
        float rT = 0.f, rC = 0.f, rS = 0.f;   // identity; suffix accumulated
        int j_hi = b - 1;
        for (;;) {
            const int idx = j_hi - 63 + lane;       // lane 63 = nearest pred
            const bool valid = (idx >= 0);
            const int cidx = c * NTILES + idx;
            unsigned long long pmask, rmask;
            int f;
            for (;;) {
                f = valid ? __hip_atomic_load(&flags[cidx], __ATOMIC_RELAXED,
                                              __HIP_MEMORY_SCOPE_AGENT)
                          : FLAG_PREFIX;            // virtual identity prefix
                pmask = __ballot(f == FLAG_PREFIX);
                rmask = __ballot(f == FLAG_PREFIX || f == FLAG_PARTIAL);
                if (pmask) {
                    int Lp = 63 - __builtin_clzll(pmask);
                    unsigned long long need =
                        (Lp == 63) ? 0ULL : (~0ULL << (Lp + 1));
                    if ((rmask & need) == need) break;
                } else if (rmask == ~0ULL) {
                    break;
                }
                __builtin_amdgcn_s_sleep(2);
            }
            __threadfence();                        // acquire for data reads
            const int Lp = pmask ? (63 - __builtin_clzll(pmask)) : -1;

            float aT = 0.f, aC = 0.f, aS = 0.f;     // identity
            if (Lp >= 0) {
                if (lane == Lp) {
                    if (valid) { float4 d = pref[cidx]; aT = d.x; aC = d.y; aS = d.z; }
                } else if (lane > Lp) {
                    float4 d = part[cidx]; aT = d.x; aC = d.y; aS = d.z;
                }
            } else {
                float4 d = part[cidx]; aT = d.x; aC = d.y; aS = d.z;
            }
            // wave suffix product: lane l -> seg_l ∘ seg_{l+1} ∘ ... ∘ seg_63
#pragma unroll
            for (int d = 1; d < 64; d <<= 1) {
                float oT = __shfl_down(aT, d, 64);
                float oC = __shfl_down(aC, d, 64);
                float oS = __shfl_down(aS, d, 64);
                if (lane + d < 64) combineSeg(aT, aC, aS, oT, oC, oS, aT, aC, aS);
            }
            const int src = (Lp < 0) ? 0 : Lp;
            float wT = __shfl(aT, src, 64);
            float wC = __shfl(aC, src, 64);
            float wS = __shfl(aS, src, 64);
            combineSeg(wT, wC, wS, rT, rC, rS, rT, rC, rS);
            if (Lp >= 0) break;                     // hit a prefix: done
            j_hi -= 64;
        }
        if (lane == 0) {
            float pT, pC, pS;
            combineSeg(rT, rC, rS, sAgg[0], sAgg[1], sAgg[2], pT, pC, pS);
            pref[cid] = make_float4(pT, pC, pS, 0.f);
            __hip_atomic_store(&flags[cid], FLAG_PREFIX,
                               __ATOMIC_RELEASE, __HIP_MEMORY_SCOPE_AGENT);
            sExcl[0] = rT; sExcl[1] = rC; sExcl[2] = rS;
        }
    }
    __syncthreads();

    // ---------------- Phase 3: emit positions — round-1 K3 body ----------------
    const float dlv = dl[0];
    const float t0 = c ? the02[0] : the0[0];
    const float sx = c ? PE[0] : PS[0];
    const float sy = c ? PE[1] : PS[1];
    float s0, c0;
    __sincosf(t0, &s0, &c0);
    const float thPre = t0 + sExcl[0];
    const float pxB = sx + dlv * (c0 * sExcl[1] - s0 * sExcl[2]);
    const float pyB = sy + dlv * (s0 * sExcl[1] + c0 * sExcl[2]);

    const float base = thPre + excl;
    float cs[ITEMS], sn[ITEMS];
    float run2 = base, sxs = 0.f, sys = 0.f;
#pragma unroll
    for (int k = 0; k < ITEMS; ++k) {
        run2 += vals[k];
        __sincosf(run2, &sn[k], &cs[k]);
        sxs += cs[k]; sys += sn[k];
    }

    float ix = sxs, iy = sys;
#pragma unroll
    for (int d = 1; d < 64; d <<= 1) {
        float ox = __shfl_up(ix, d, 64);
        float oy = __shfl_up(iy, d, 64);
        if (lane >= d) { ix += ox; iy += oy; }
    }
    if (lane == 63) { sWx[wave] = ix; sWy[wave] = iy; }
    __syncthreads();
    float wpx = 0.f, wpy = 0.f;
#pragma unroll
    for (int w = 0; w < WAVES; ++w) {
        if (w < wave) { wpx += sWx[w]; wpy += sWy[w]; }
    }
    const float ex = wpx + ix - sxs;
    const float ey = wpy + iy - sys;

    float px = pxB + dlv * ex;
    float py = pyB + dlv * ey;

    float2* __restrict__ o2 =
        reinterpret_cast<float2*>(out) + (size_t)c * (NSEG + 1);
    const size_t gbase = (size_t)b * TILE + (size_t)t * ITEMS;
#pragma unroll
    for (int k = 0; k < ITEMS; ++k) {
        px += dlv * cs[k];
        py += dlv * sn[k];
        o2[gbase + k + 1] = make_float2(px, py);
    }
    if (b == 0 && t == 0) {
        o2[0] = make_float2(sx, sy);
    }
}

extern "C" void kernel_launch(void* const* d_in, const int* in_sizes, int n_in,
                              void* d_out, int out_size, void* d_ws, size_t ws_size,
                              hipStream_t stream) {
    const float* vec   = (const float*)d_in[0];
    const float* vec2  = (const float*)d_in[1];
    const float* the0  = (const float*)d_in[2];
    const float* the02 = (const float*)d_in[3];
    const float* PS    = (const float*)d_in[4];
    const float* PE    = (const float*)d_in[5];
    const float* dl    = (const float*)d_in[6];
    float* out = (float*)d_out;

    // ws layout: flags [2*1024] ints (poison != 1/2 => "not ready", no init
    // needed); partial float4[2*1024] @ +8KB; prefix float4[2*1024] @ +40KB.
    char* wsb = (char*)d_ws;
    int*    flags = (int*)wsb;
    float4* part  = (float4*)(wsb + 8 * 1024);
    float4* pref  = (float4*)(wsb + 40 * 1024);

    k_fused<<<dim3(NTILES, 2), BLOCK, 0, stream>>>(
        vec, vec2, the0, the02, PS, PE, dl, flags, part, pref, out);
}

// Round 4
// 111.231 us; speedup vs baseline: 4.9463x; 4.9463x over previous
//
#include <hip/hip_runtime.h>

#define NSEG   4194304
#define BLOCK  256
#define ITEMS  16
#define TILE   (BLOCK * ITEMS)     // 4096
#define NTILES (NSEG / TILE)       // 1024
#define WAVES  (BLOCK / 64)        // 4

static_assert(NSEG % TILE == 0, "tile must divide N");

// Segment monoid: T = sum of angles, C/S = sum of cos/sin of segment-local
// inclusive cumulative angle. combine(a, b) = "a followed by b".
// Identity = (0,0,0). Inputs by value (safe to alias outputs).
__device__ __forceinline__ void combineSeg(float aT, float aC, float aS,
                                           float bT, float bC, float bS,
                                           float& oT, float& oC, float& oS) {
    float s, c;
    __sincosf(aT, &s, &c);
    oT = aT + bT;
    oC = aC + c * bC - s * bS;
    oS = aS + s * bC + c * bS;
}

// ---------------- K1: per-tile (T, C, S) summaries (round-1 body) ----------------
__global__ __launch_bounds__(BLOCK) void k_tilesum(
        const float* __restrict__ vec, const float* __restrict__ vec2,
        float4* __restrict__ part) {
    const int c = blockIdx.y;
    const int b = blockIdx.x;
    const int t = threadIdx.x;
    const int lane = t & 63, wave = t >> 6;
    const float* __restrict__ v = c ? vec2 : vec;

    __shared__ float sW[WAVES], sRC[WAVES], sRS[WAVES];

    const float4* __restrict__ p =
        reinterpret_cast<const float4*>(v + (size_t)b * TILE) +
        (size_t)t * (ITEMS / 4);
    float vals[ITEMS];
#pragma unroll
    for (int q = 0; q < ITEMS / 4; ++q) {
        float4 a = p[q];
        vals[q * 4 + 0] = a.x; vals[q * 4 + 1] = a.y;
        vals[q * 4 + 2] = a.z; vals[q * 4 + 3] = a.w;
    }
    float tsum = 0.f;
#pragma unroll
    for (int k = 0; k < ITEMS; ++k) tsum += vals[k];

    float incl = tsum;
#pragma unroll
    for (int d = 1; d < 64; d <<= 1) {
        float o = __shfl_up(incl, d, 64);
        if (lane >= d) incl += o;
    }
    if (lane == 63) sW[wave] = incl;
    __syncthreads();
    float wpre = 0.f, tot = 0.f;
#pragma unroll
    for (int w = 0; w < WAVES; ++w) {
        float x = sW[w];
        if (w < wave) wpre += x;
        tot += x;
    }
    const float excl = wpre + incl - tsum;

    float run = excl, C = 0.f, S = 0.f;
#pragma unroll
    for (int k = 0; k < ITEMS; ++k) {
        run += vals[k];
        float sn, cs;
        __sincosf(run, &sn, &cs);
        C += cs; S += sn;
    }
#pragma unroll
    for (int d = 32; d > 0; d >>= 1) {
        C += __shfl_down(C, d, 64);
        S += __shfl_down(S, d, 64);
    }
    if (lane == 0) { sRC[wave] = C; sRS[wave] = S; }
    __syncthreads();
    if (t == 0) {
        float Ct = 0.f, St = 0.f;
#pragma unroll
        for (int w = 0; w < WAVES; ++w) { Ct += sRC[w]; St += sRS[w]; }
        part[c * NTILES + b] = make_float4(tot, Ct, St, 0.f);
    }
}

// ---------------- K2: redundant summary-scan + emit with LDS-transposed stores ----
__global__ __launch_bounds__(BLOCK, 4) void k_emit(
        const float* __restrict__ vec, const float* __restrict__ vec2,
        const float* __restrict__ the0, const float* __restrict__ the02,
        const float* __restrict__ PS, const float* __restrict__ PE,
        const float* __restrict__ dl,
        const float4* __restrict__ part, float* __restrict__ out) {
    const int b = blockIdx.x;
    const int c = blockIdx.y;
    const int t = threadIdx.x;
    const int lane = t & 63, wave = t >> 6;
    const float* __restrict__ v = c ? vec2 : vec;

    __shared__ float sMT[WAVES], sMC[WAVES], sMS[WAVES];
    __shared__ float sPre[3];
    __shared__ float sW[WAVES], sWx[WAVES], sWy[WAVES];
    __shared__ float smX[128 * 17], smY[128 * 17];   // 17-padded rows: 2-way max

    // ---- Phase A: in-block scan of this curve's 1024 tile summaries; keep [b]'s
    //      exclusive prefix. Deterministic, identical in every block.
    {
        const float4* __restrict__ pp = part + (size_t)c * NTILES;
        float aT[4], aC[4], aS[4];
        float T = 0.f, C = 0.f, S = 0.f;
#pragma unroll
        for (int j = 0; j < 4; ++j) {
            float4 d4 = pp[t * 4 + j];
            aT[j] = d4.x; aC[j] = d4.y; aS[j] = d4.z;
            combineSeg(T, C, S, aT[j], aC[j], aS[j], T, C, S);
        }
        float iT = T, iC = C, iS = S;
#pragma unroll
        for (int d = 1; d < 64; d <<= 1) {
            float oT = __shfl_up(iT, d, 64);
            float oC = __shfl_up(iC, d, 64);
            float oS = __shfl_up(iS, d, 64);
            if (lane >= d) combineSeg(oT, oC, oS, iT, iC, iS, iT, iC, iS);
        }
        float pT = __shfl_up(iT, 1, 64);
        float pC = __shfl_up(iC, 1, 64);
        float pS = __shfl_up(iS, 1, 64);
        float eT = (lane == 0) ? 0.f : pT;
        float eC = (lane == 0) ? 0.f : pC;
        float eS = (lane == 0) ? 0.f : pS;
        if (lane == 63) { sMT[wave] = iT; sMC[wave] = iC; sMS[wave] = iS; }
        __syncthreads();
        float wT = 0.f, wC = 0.f, wS = 0.f;
#pragma unroll
        for (int w = 0; w < WAVES; ++w) {
            if (w < wave) combineSeg(wT, wC, wS, sMT[w], sMC[w], sMS[w], wT, wC, wS);
        }
        float xT, xC, xS;   // thread-exclusive prefix (tiles < 4t)
        combineSeg(wT, wC, wS, eT, eC, eS, xT, xC, xS);

        if (b == 0) {
            if (t == 0) { sPre[0] = 0.f; sPre[1] = 0.f; sPre[2] = 0.f; }
        } else {
            const int q = (b - 1) >> 2;
            if (t == q) {
                float PT = xT, PC = xC, PZ = xS;
                const int m = (b - 1) & 3;
                for (int j = 0; j <= m; ++j)
                    combineSeg(PT, PC, PZ, aT[j], aC[j], aS[j], PT, PC, PZ);
                sPre[0] = PT; sPre[1] = PC; sPre[2] = PZ;
            }
        }
        __syncthreads();
    }

    const float t0 = c ? the02[0] : the0[0];
    const float sx = c ? PE[0] : PS[0];
    const float sy = c ? PE[1] : PS[1];
    const float dlv = dl[0];
    float s0, c0;
    __sincosf(t0, &s0, &c0);
    const float thPre = t0 + sPre[0];
    const float pxB = sx + dlv * (c0 * sPre[1] - s0 * sPre[2]);
    const float pyB = sy + dlv * (s0 * sPre[1] + c0 * sPre[2]);

    // ---- Phase B: intra-tile positions (round-1 K3 body) ----
    const float4* __restrict__ p =
        reinterpret_cast<const float4*>(v + (size_t)b * TILE) +
        (size_t)t * (ITEMS / 4);
    float vals[ITEMS];
#pragma unroll
    for (int q = 0; q < ITEMS / 4; ++q) {
        float4 a = p[q];
        vals[q * 4 + 0] = a.x; vals[q * 4 + 1] = a.y;
        vals[q * 4 + 2] = a.z; vals[q * 4 + 3] = a.w;
    }
    float tsum = 0.f;
#pragma unroll
    for (int k = 0; k < ITEMS; ++k) tsum += vals[k];

    float incl = tsum;
#pragma unroll
    for (int d = 1; d < 64; d <<= 1) {
        float o = __shfl_up(incl, d, 64);
        if (lane >= d) incl += o;
    }
    if (lane == 63) sW[wave] = incl;
    __syncthreads();
    float wpre = 0.f;
#pragma unroll
    for (int w = 0; w < WAVES; ++w) {
        float x = sW[w];
        if (w < wave) wpre += x;
    }
    const float angExcl = wpre + incl - tsum;

    const float base = thPre + angExcl;
    float cs[ITEMS], sn[ITEMS];
    float run2 = base, sxs = 0.f, sys = 0.f;
#pragma unroll
    for (int k = 0; k < ITEMS; ++k) {
        run2 += vals[k];
        __sincosf(run2, &sn[k], &cs[k]);
        sxs += cs[k]; sys += sn[k];
    }

    float ix = sxs, iy = sys;
#pragma unroll
    for (int d = 1; d < 64; d <<= 1) {
        float ox = __shfl_up(ix, d, 64);
        float oy = __shfl_up(iy, d, 64);
        if (lane >= d) { ix += ox; iy += oy; }
    }
    if (lane == 63) { sWx[wave] = ix; sWy[wave] = iy; }
    __syncthreads();
    float wpx = 0.f, wpy = 0.f;
#pragma unroll
    for (int w = 0; w < WAVES; ++w) {
        if (w < wave) { wpx += sWx[w]; wpy += sWy[w]; }
    }
    const float ex = wpx + ix - sxs;
    const float ey = wpy + iy - sys;

    float px = pxB + dlv * ex;    // position BEFORE this thread's first element
    float py = pyB + dlv * ey;

    // ---- Phase C: stage through LDS, store coalesced float2 runs ----
    float2* __restrict__ o2 =
        reinterpret_cast<float2*>(out) + (size_t)c * (NSEG + 1);
    const int halfId = t >> 7;          // this thread's elements live in half 0/1
    const int row = t & 127;

#pragma unroll
    for (int h = 0; h < 2; ++h) {
        __syncthreads();                // protect smX/smY reuse across halves
        if (halfId == h) {
            float qx = px, qy = py;
#pragma unroll
            for (int k = 0; k < ITEMS; ++k) {
                qx += dlv * cs[k];
                qy += dlv * sn[k];
                smX[row * 17 + k] = qx;
                smY[row * 17 + k] = qy;
            }
        }
        __syncthreads();
        const size_t eBase = (size_t)b * TILE + (size_t)h * 2048 + 1;
#pragma unroll
        for (int r = 0; r < 8; ++r) {
            const int e = r * 256 + t;  // element within this half
            const float xx = smX[(e >> 4) * 17 + (e & 15)];
            const float yy = smY[(e >> 4) * 17 + (e & 15)];
            o2[eBase + e] = make_float2(xx, yy);  // lanes → consecutive float2
        }
    }
    if (b == 0 && t == 0) {
        o2[0] = make_float2(sx, sy);
    }
}

extern "C" void kernel_launch(void* const* d_in, const int* in_sizes, int n_in,
                              void* d_out, int out_size, void* d_ws, size_t ws_size,
                              hipStream_t stream) {
    const float* vec   = (const float*)d_in[0];
    const float* vec2  = (const float*)d_in[1];
    const float* the0  = (const float*)d_in[2];
    const float* the02 = (const float*)d_in[3];
    const float* PS    = (const float*)d_in[4];
    const float* PE    = (const float*)d_in[5];
    const float* dl    = (const float*)d_in[6];
    float* out = (float*)d_out;
    float4* part = (float4*)d_ws;   // 2 * 1024 float4 = 32 KB

    dim3 grid(NTILES, 2);
    k_tilesum<<<grid, BLOCK, 0, stream>>>(vec, vec2, part);
    k_emit<<<grid, BLOCK, 0, stream>>>(vec, vec2, the0, the02, PS, PE, dl,
                                       part, out);
}